// Round 25
// baseline (63.452 us; speedup 1.0000x reference)
//
#include <hip/hip_runtime.h>
#include <hip/hip_bf16.h>

#define BCH 32   // B*C heads
#define NN  2048
#define DD  64   // F = H = O

typedef __attribute__((ext_vector_type(8)))  __bf16 bf16x8;
typedef __attribute__((ext_vector_type(4)))  __bf16 bf16x4;
typedef __attribute__((ext_vector_type(4)))  float  f32x4;
typedef __attribute__((ext_vector_type(16))) float  f32x16;
typedef __attribute__((ext_vector_type(2)))  int    i32x2;
typedef __attribute__((ext_vector_type(4)))  int    i32x4;
typedef __attribute__((ext_vector_type(2)))  unsigned int u32x2;

__device__ inline f32x4 mfma16(bf16x8 a, bf16x8 b, f32x4 c) {
    return __builtin_amdgcn_mfma_f32_16x16x32_bf16(a, b, c, 0, 0, 0);
}
__device__ inline f32x16 mfma32(bf16x8 a, bf16x8 b, f32x16 c) {
    return __builtin_amdgcn_mfma_f32_32x32x16_bf16(a, b, c, 0, 0, 0);
}
// permlane32_swap BUILTIN (validated round 9)
__device__ inline void plswap(int& a, int& b) {
    u32x2 r = __builtin_amdgcn_permlane32_swap((unsigned)a, (unsigned)b, false, false);
    a = (int)r[0];
    b = (int)r[1];
}

// ---------------------------------------------------------------------------
// Kernel 1 v5: MLP-boosted prep. grid 2048 (32 bc x 64 half-strips of 32 n),
// block 256 = 4 waves; wave w owns h-block w; nb in {0,1}. 6 blocks/CU ->
// 3x in-flight memory vs v1 (prep was latency/MLP-bound, not work-bound).
// Store maps = round-20 phase-A maps (HW-validated) with sh&1 for w&1, w for hb.
//   E1F/E2F [bc][st][c][r], VTF [bc][st][d][o] fragment-linear (validated).
// ---------------------------------------------------------------------------
__global__ __launch_bounds__(256, 6) void prep_kernel(
    const float* __restrict__ x,
    const float* __restrict__ W1, const float* __restrict__ b1,
    const float* __restrict__ W2, const float* __restrict__ b2,
    const float* __restrict__ W3,
    __bf16* __restrict__ e1f, __bf16* __restrict__ e2f, __bf16* __restrict__ vtf)
{
    const int t   = threadIdx.x;
    const int blk = blockIdx.x;
    const int bc  = blk >> 6, sh = blk & 63;         // half-strip of 32 rows
    const long grow = (long)bc * NN + sh * 32;
    const int w = t >> 6, l = t & 63, lg = l >> 4, li = l & 15;

    bf16x8 a[2][2];
    #pragma unroll
    for (int nb = 0; nb < 2; ++nb)
        #pragma unroll
        for (int kk = 0; kk < 2; ++kk) {
            const float* p = x + (grow + nb * 16 + li) * DD + kk * 32 + lg * 8;
            f32x4 v0 = *(const f32x4*)p, v1 = *(const f32x4*)(p + 4);
            #pragma unroll
            for (int j = 0; j < 4; ++j) {
                a[nb][kk][j]     = (__bf16)v0[j];
                a[nb][kk][4 + j] = (__bf16)v1[j];
            }
        }

    bf16x8 wf1[2], wf2[2], wf3[2];
    #pragma unroll
    for (int kk = 0; kk < 2; ++kk) {
        const float* p1 = W1 + (w * 16 + li) * DD + kk * 32 + lg * 8;
        const float* p2 = W2 + (w * 16 + li) * DD + kk * 32 + lg * 8;
        const float* p3 = W3 + (w * 16 + li) * DD + kk * 32 + lg * 8;
        f32x4 u0 = *(const f32x4*)p1, u1 = *(const f32x4*)(p1 + 4);
        f32x4 v0 = *(const f32x4*)p2, v1 = *(const f32x4*)(p2 + 4);
        f32x4 t0 = *(const f32x4*)p3, t1 = *(const f32x4*)(p3 + 4);
        #pragma unroll
        for (int j = 0; j < 4; ++j) {
            wf1[kk][j] = (__bf16)u0[j]; wf1[kk][4 + j] = (__bf16)u1[j];
            wf2[kk][j] = (__bf16)v0[j]; wf2[kk][4 + j] = (__bf16)v1[j];
            wf3[kk][j] = (__bf16)t0[j]; wf3[kk][4 + j] = (__bf16)t1[j];
        }
    }
    const f32x4 bq1 = *(const f32x4*)(b1 + w * 16 + lg * 4);
    const f32x4 bq2 = *(const f32x4*)(b2 + w * 16 + lg * 4);

    const size_t tbase = (size_t)(bc * 32 + (sh >> 1)) * 4096;
    const int rh = (sh & 1) * 32;                    // row offset within 64-tile

    #pragma unroll
    for (int nb = 0; nb < 2; ++nb) {
        f32x4 acc1 = {0.f,0.f,0.f,0.f}, acc2 = {0.f,0.f,0.f,0.f}, acc3 = {0.f,0.f,0.f,0.f};
        #pragma unroll
        for (int kk = 0; kk < 2; ++kk) {
            acc1 = mfma16(wf1[kk], a[nb][kk], acc1);   // D[h][n]
            acc2 = mfma16(wf2[kk], a[nb][kk], acc2);   // D[h][n]
            acc3 = mfma16(a[nb][kk], wf3[kk], acc3);   // D[n][o]
        }
        bf16x4 q1, q2, q3;
        #pragma unroll
        for (int r = 0; r < 4; ++r) {
            q1[r] = (__bf16)(acc1[r] + bq1[r]);
            q2[r] = (__bf16)(acc2[r] + bq2[r]);
            q3[r] = (__bf16)acc3[r];
        }
        *(bf16x4*)&e1f[tbase + (w * 2 + (lg >> 1)) * 512 + (rh + nb * 16 + li) * 8 + (lg & 1) * 4] = q1;
        *(bf16x4*)&e2f[tbase + (w * 2 + (lg >> 1)) * 512 + (rh + nb * 16 + li) * 8 + (lg & 1) * 4] = q2;
        *(bf16x4*)&vtf[tbase + ((sh & 1) * 4 + nb * 2 + (lg >> 1)) * 512 + (w * 16 + li) * 8 + (lg & 1) * 4] = q3;
    }
}

// ---------------------------------------------------------------------------
// Kernel 2 (round-23 v12 EXACTLY, best measured 58.9): T15 pipeline, LDS-free
// barrier-free K-loop, 64n/wave, CU-sharing head map, permlane PV.
// ---------------------------------------------------------------------------
__global__ __launch_bounds__(128, 2) void fused_kernel(
    const __bf16* __restrict__ e1f, const __bf16* __restrict__ e2f,
    const __bf16* __restrict__ vtf, const float* __restrict__ b3,
    float* __restrict__ out)
{
    __shared__ float scratch[4096];      // epilogue m-half combine (16KB)

    const int t   = threadIdx.x;
    const int bid = blockIdx.x;
    const int x8 = bid & 7, jj = bid >> 3;          // jj in 0..127
    const int bc = x8 * 4 + (jj & 3), nt = jj >> 2;

    const int wm = t >> 6, l = t & 63;
    const int l31 = l & 31, hi5 = l >> 5;
    const int nbase = nt * 64;

    const float bv0 = b3[l31], bv1 = b3[32 + l31];

    bf16x8 e1v[2][4];
    #pragma unroll
    for (int nb = 0; nb < 2; ++nb) {
        const __bf16* p = e1f + ((size_t)bc * 32 + nt) * 4096 + hi5 * 512 + (nb * 32 + l31) * 8;
        #pragma unroll
        for (int kk = 0; kk < 4; ++kk)
            e1v[nb][kk] = *(const bf16x8*)(p + kk * 1024);
    }

    f32x16 fz;
    #pragma unroll
    for (int i = 0; i < 16; ++i) fz[i] = 0.f;
    f32x16 hacc[2][2];   // [nb][fb]
    #pragma unroll
    for (int nb = 0; nb < 2; ++nb)
        #pragma unroll
        for (int fb = 0; fb < 2; ++fb)
            #pragma unroll
            for (int i = 0; i < 16; ++i) hacc[nb][fb][i] = 0.f;

    const __bf16* E2 = e2f + (size_t)bc * 131072 + hi5 * 512 + (wm * 32 + l31) * 8;
    const __bf16* VT = vtf + (size_t)bc * 131072 + (wm * 4 + hi5) * 512 + l31 * 8;

    auto loadEF = [&](int kt, bf16x8 (&ef)[4]) {
        const __bf16* p = E2 + (size_t)kt * 4096;
        #pragma unroll
        for (int kk = 0; kk < 4; ++kk)
            ef[kk] = *(const bf16x8*)(p + kk * 1024);
    };
    auto loadVF = [&](int kt, bf16x8 (&vf)[4]) {
        const __bf16* p = VT + (size_t)kt * 4096;
        #pragma unroll
        for (int kk2 = 0; kk2 < 2; ++kk2) {
            vf[kk2 * 2 + 0] = *(const bf16x8*)(p + kk2 * 1024);
            vf[kk2 * 2 + 1] = *(const bf16x8*)(p + kk2 * 1024 + 256);
        }
    };
    auto computeS = [&](bf16x8 (&ef)[4], f32x16 (&sT)[2]) {
        sT[0] = mfma32(ef[0], e1v[0][0], fz);
        sT[1] = mfma32(ef[0], e1v[1][0], fz);
        #pragma unroll
        for (int kk = 1; kk < 4; ++kk) {
            sT[0] = mfma32(ef[kk], e1v[0][kk], sT[0]);
            sT[1] = mfma32(ef[kk], e1v[1][kk], sT[1]);
        }
    };
    auto packQ = [&](const f32x16 (&sT)[2], i32x2 (&Q)[2][4]) {
        #pragma unroll
        for (int nb = 0; nb < 2; ++nb)
            #pragma unroll
            for (int g = 0; g < 4; ++g) {
                bf16x4 q0;
                #pragma unroll
                for (int r = 0; r < 4; ++r)
                    q0[r] = (__bf16)fmaxf(sT[nb][4 * g + r], 0.f);
                Q[nb][g] = __builtin_bit_cast(i32x2, q0);
            }
    };
    auto doPV = [&](i32x2 (&Q)[2][4], bf16x8 (&vf)[4]) {
        #pragma unroll
        for (int kk2 = 0; kk2 < 2; ++kk2)
            #pragma unroll
            for (int nb = 0; nb < 2; ++nb) {
                int a0 = Q[nb][2 * kk2][0],     a1 = Q[nb][2 * kk2][1];
                int b0 = Q[nb][2 * kk2 + 1][0], b1 = Q[nb][2 * kk2 + 1][1];
                plswap(a0, b0);
                plswap(a1, b1);
                i32x4 pfi = { a0, a1, b0, b1 };
                bf16x8 pf = __builtin_bit_cast(bf16x8, pfi);
                hacc[nb][0] = mfma32(pf, vf[kk2 * 2 + 0], hacc[nb][0]);
                hacc[nb][1] = mfma32(pf, vf[kk2 * 2 + 1], hacc[nb][1]);
            }
    };

    bf16x8 efA[4], vfA[4], efB[4], vfB[4];
    f32x16 sTA[2], sTB[2];
    i32x2 Q[2][4];

    loadEF(0, efA); loadVF(0, vfA);
    loadEF(1, efB); loadVF(1, vfB);
    computeS(efA, sTA);

    for (int j = 0; j < 15; ++j) {
        loadEF(2 * j + 2, efA);
        computeS(efB, sTB);      // MFMA, tile 2j+1
        packQ(sTA, Q);           // VALU, tile 2j
        doPV(Q, vfA);            // MFMA, tile 2j
        loadVF(2 * j + 2, vfA);

        loadEF(2 * j + 3, efB);
        computeS(efA, sTA);      // MFMA, tile 2j+2
        packQ(sTB, Q);           // VALU, tile 2j+1
        doPV(Q, vfB);            // MFMA, tile 2j+1
        loadVF(2 * j + 3, vfB);
    }

    packQ(sTA, Q);
    doPV(Q, vfA);
    computeS(efB, sTB);
    packQ(sTB, Q);
    doPV(Q, vfB);

    // ---- epilogue: combine m-halves via LDS, add b3, store fp32 ----
    if (wm == 1) {
        #pragma unroll
        for (int nb = 0; nb < 2; ++nb)
            #pragma unroll
            for (int q = 0; q < 8; ++q) {
                f32x4 v;
                #pragma unroll
                for (int r = 0; r < 4; ++r) {
                    const int idx = q * 4 + r;          // 0..31
                    v[r] = hacc[nb][idx >> 4][idx & 15];
                }
                *(f32x4*)&scratch[nb * 2048 + q * 256 + l * 4] = v;
            }
    }
    __syncthreads();
    if (wm == 0) {
        #pragma unroll
        for (int nb = 0; nb < 2; ++nb)
            #pragma unroll
            for (int q = 0; q < 8; ++q) {
                f32x4 v = *(const f32x4*)&scratch[nb * 2048 + q * 256 + l * 4];
                #pragma unroll
                for (int r = 0; r < 4; ++r) {
                    const int idx = q * 4 + r;
                    hacc[nb][idx >> 4][idx & 15] += v[r];
                }
            }
        #pragma unroll
        for (int nb = 0; nb < 2; ++nb) {
            const size_t ob = ((size_t)bc * NN + nbase + nb * 32) * DD;
            #pragma unroll
            for (int reg = 0; reg < 16; ++reg) {
                const int n = (reg & 3) + 8 * (reg >> 2) + 4 * hi5;
                out[ob + (size_t)n * DD + l31]      = hacc[nb][0][reg] + bv0;
                out[ob + (size_t)n * DD + 32 + l31] = hacc[nb][1][reg] + bv1;
            }
        }
    }
}

extern "C" void kernel_launch(void* const* d_in, const int* in_sizes, int n_in,
                              void* d_out, int out_size, void* d_ws, size_t ws_size,
                              hipStream_t stream) {
    const float* x  = (const float*)d_in[0];
    const float* W1 = (const float*)d_in[1];
    const float* b1 = (const float*)d_in[2];
    const float* W2 = (const float*)d_in[3];
    const float* b2 = (const float*)d_in[4];
    const float* W3 = (const float*)d_in[5];
    const float* b3 = (const float*)d_in[6];
    float* out = (float*)d_out;

    __bf16* e1f = (__bf16*)d_ws;                      // 8 MB fragment-linear
    __bf16* e2f = e1f + (size_t)BCH * NN * DD;        // 8 MB fragment-linear
    __bf16* vtf = e2f + (size_t)BCH * NN * DD;        // 8 MB fragment-linear

    prep_kernel<<<dim3(2048), dim3(256), 0, stream>>>(x, W1, b1, W2, b2, W3, e1f, e2f, vtf);
    fused_kernel<<<dim3(1024), dim3(128), 0, stream>>>(e1f, e2f, vtf, b3, out);
}

// Round 26
// 58.985 us; speedup vs baseline: 1.0757x; 1.0757x over previous
//
#include <hip/hip_runtime.h>
#include <hip/hip_bf16.h>

#define BCH 32   // B*C heads
#define NN  2048
#define DD  64   // F = H = O

typedef __attribute__((ext_vector_type(8)))  __bf16 bf16x8;
typedef __attribute__((ext_vector_type(4)))  __bf16 bf16x4;
typedef __attribute__((ext_vector_type(4)))  float  f32x4;
typedef __attribute__((ext_vector_type(16))) float  f32x16;
typedef __attribute__((ext_vector_type(2)))  int    i32x2;
typedef __attribute__((ext_vector_type(4)))  int    i32x4;
typedef __attribute__((ext_vector_type(2)))  unsigned int u32x2;

__device__ inline f32x4 mfma16(bf16x8 a, bf16x8 b, f32x4 c) {
    return __builtin_amdgcn_mfma_f32_16x16x32_bf16(a, b, c, 0, 0, 0);
}
__device__ inline f32x16 mfma32(bf16x8 a, bf16x8 b, f32x16 c) {
    return __builtin_amdgcn_mfma_f32_32x32x16_bf16(a, b, c, 0, 0, 0);
}
// permlane32_swap BUILTIN (validated round 9)
__device__ inline void plswap(int& a, int& b) {
    u32x2 r = __builtin_amdgcn_permlane32_swap((unsigned)a, (unsigned)b, false, false);
    a = (int)r[0];
    b = (int)r[1];
}

// ---------------------------------------------------------------------------
// Kernel 1 (round-15/23 shape — best measured): fragment-linear outputs
//   E1F [bc][nt64][c][r], E2F [bc][kt64][c][r], VTF [bc][kt64][d][o]
// grid 1024 (32 bc x 32 strips), block 256 = 4 waves; wave w owns h-block w.
// ---------------------------------------------------------------------------
__global__ __launch_bounds__(256) void prep_kernel(
    const float* __restrict__ x,
    const float* __restrict__ W1, const float* __restrict__ b1,
    const float* __restrict__ W2, const float* __restrict__ b2,
    const float* __restrict__ W3,
    __bf16* __restrict__ e1f, __bf16* __restrict__ e2f, __bf16* __restrict__ vtf)
{
    const int t   = threadIdx.x;
    const int blk = blockIdx.x;
    const int bc  = blk >> 5, st = blk & 31;
    const long grow = (long)bc * NN + st * 64;
    const int w = t >> 6, l = t & 63, lg = l >> 4, li = l & 15;

    bf16x8 a[4][2];
    #pragma unroll
    for (int nb = 0; nb < 4; ++nb)
        #pragma unroll
        for (int kk = 0; kk < 2; ++kk) {
            const float* p = x + (grow + nb * 16 + li) * DD + kk * 32 + lg * 8;
            f32x4 v0 = *(const f32x4*)p, v1 = *(const f32x4*)(p + 4);
            #pragma unroll
            for (int j = 0; j < 4; ++j) {
                a[nb][kk][j]     = (__bf16)v0[j];
                a[nb][kk][4 + j] = (__bf16)v1[j];
            }
        }

    bf16x8 wf1[2], wf2[2], wf3[2];
    #pragma unroll
    for (int kk = 0; kk < 2; ++kk) {
        const float* p1 = W1 + (w * 16 + li) * DD + kk * 32 + lg * 8;
        const float* p2 = W2 + (w * 16 + li) * DD + kk * 32 + lg * 8;
        const float* p3 = W3 + (w * 16 + li) * DD + kk * 32 + lg * 8;
        f32x4 u0 = *(const f32x4*)p1, u1 = *(const f32x4*)(p1 + 4);
        f32x4 v0 = *(const f32x4*)p2, v1 = *(const f32x4*)(p2 + 4);
        f32x4 t0 = *(const f32x4*)p3, t1 = *(const f32x4*)(p3 + 4);
        #pragma unroll
        for (int j = 0; j < 4; ++j) {
            wf1[kk][j] = (__bf16)u0[j]; wf1[kk][4 + j] = (__bf16)u1[j];
            wf2[kk][j] = (__bf16)v0[j]; wf2[kk][4 + j] = (__bf16)v1[j];
            wf3[kk][j] = (__bf16)t0[j]; wf3[kk][4 + j] = (__bf16)t1[j];
        }
    }
    const f32x4 bq1 = *(const f32x4*)(b1 + w * 16 + lg * 4);
    const f32x4 bq2 = *(const f32x4*)(b2 + w * 16 + lg * 4);

    const size_t tbase = (size_t)(bc * 32 + st) * 4096;

    #pragma unroll
    for (int nb = 0; nb < 4; ++nb) {
        f32x4 acc1 = {0.f,0.f,0.f,0.f}, acc2 = {0.f,0.f,0.f,0.f}, acc3 = {0.f,0.f,0.f,0.f};
        #pragma unroll
        for (int kk = 0; kk < 2; ++kk) {
            acc1 = mfma16(wf1[kk], a[nb][kk], acc1);   // D[h][n]
            acc2 = mfma16(wf2[kk], a[nb][kk], acc2);   // D[h][n]
            acc3 = mfma16(a[nb][kk], wf3[kk], acc3);   // D[n][o]
        }
        bf16x4 q1, q2, q3;
        #pragma unroll
        for (int r = 0; r < 4; ++r) {
            q1[r] = (__bf16)(acc1[r] + bq1[r]);
            q2[r] = (__bf16)(acc2[r] + bq2[r]);
            q3[r] = (__bf16)acc3[r];
        }
        *(bf16x4*)&e1f[tbase + (w * 2 + (lg >> 1)) * 512 + (nb * 16 + li) * 8 + (lg & 1) * 4] = q1;
        *(bf16x4*)&e2f[tbase + (w * 2 + (lg >> 1)) * 512 + (nb * 16 + li) * 8 + (lg & 1) * 4] = q2;
        *(bf16x4*)&vtf[tbase + (nb * 2 + (lg >> 1)) * 512 + (w * 16 + li) * 8 + (lg & 1) * 4] = q3;
    }
}

// ---------------------------------------------------------------------------
// Kernel 2 (round-23 v12 EXACTLY — best measured 58.9 µs total): T15 pipeline,
// LDS-free barrier-free K-loop, 64n/wave, CU-sharing head map, permlane PV.
// ---------------------------------------------------------------------------
__global__ __launch_bounds__(128, 2) void fused_kernel(
    const __bf16* __restrict__ e1f, const __bf16* __restrict__ e2f,
    const __bf16* __restrict__ vtf, const float* __restrict__ b3,
    float* __restrict__ out)
{
    __shared__ float scratch[4096];      // epilogue m-half combine (16KB)

    const int t   = threadIdx.x;
    const int bid = blockIdx.x;
    const int x8 = bid & 7, jj = bid >> 3;          // jj in 0..127
    const int bc = x8 * 4 + (jj & 3), nt = jj >> 2;

    const int wm = t >> 6, l = t & 63;
    const int l31 = l & 31, hi5 = l >> 5;
    const int nbase = nt * 64;

    const float bv0 = b3[l31], bv1 = b3[32 + l31];

    bf16x8 e1v[2][4];
    #pragma unroll
    for (int nb = 0; nb < 2; ++nb) {
        const __bf16* p = e1f + ((size_t)bc * 32 + nt) * 4096 + hi5 * 512 + (nb * 32 + l31) * 8;
        #pragma unroll
        for (int kk = 0; kk < 4; ++kk)
            e1v[nb][kk] = *(const bf16x8*)(p + kk * 1024);
    }

    f32x16 fz;
    #pragma unroll
    for (int i = 0; i < 16; ++i) fz[i] = 0.f;
    f32x16 hacc[2][2];   // [nb][fb]
    #pragma unroll
    for (int nb = 0; nb < 2; ++nb)
        #pragma unroll
        for (int fb = 0; fb < 2; ++fb)
            #pragma unroll
            for (int i = 0; i < 16; ++i) hacc[nb][fb][i] = 0.f;

    const __bf16* E2 = e2f + (size_t)bc * 131072 + hi5 * 512 + (wm * 32 + l31) * 8;
    const __bf16* VT = vtf + (size_t)bc * 131072 + (wm * 4 + hi5) * 512 + l31 * 8;

    auto loadEF = [&](int kt, bf16x8 (&ef)[4]) {
        const __bf16* p = E2 + (size_t)kt * 4096;
        #pragma unroll
        for (int kk = 0; kk < 4; ++kk)
            ef[kk] = *(const bf16x8*)(p + kk * 1024);
    };
    auto loadVF = [&](int kt, bf16x8 (&vf)[4]) {
        const __bf16* p = VT + (size_t)kt * 4096;
        #pragma unroll
        for (int kk2 = 0; kk2 < 2; ++kk2) {
            vf[kk2 * 2 + 0] = *(const bf16x8*)(p + kk2 * 1024);
            vf[kk2 * 2 + 1] = *(const bf16x8*)(p + kk2 * 1024 + 256);
        }
    };
    auto computeS = [&](bf16x8 (&ef)[4], f32x16 (&sT)[2]) {
        sT[0] = mfma32(ef[0], e1v[0][0], fz);
        sT[1] = mfma32(ef[0], e1v[1][0], fz);
        #pragma unroll
        for (int kk = 1; kk < 4; ++kk) {
            sT[0] = mfma32(ef[kk], e1v[0][kk], sT[0]);
            sT[1] = mfma32(ef[kk], e1v[1][kk], sT[1]);
        }
    };
    auto packQ = [&](const f32x16 (&sT)[2], i32x2 (&Q)[2][4]) {
        #pragma unroll
        for (int nb = 0; nb < 2; ++nb)
            #pragma unroll
            for (int g = 0; g < 4; ++g) {
                bf16x4 q0;
                #pragma unroll
                for (int r = 0; r < 4; ++r)
                    q0[r] = (__bf16)fmaxf(sT[nb][4 * g + r], 0.f);
                Q[nb][g] = __builtin_bit_cast(i32x2, q0);
            }
    };
    auto doPV = [&](i32x2 (&Q)[2][4], bf16x8 (&vf)[4]) {
        #pragma unroll
        for (int kk2 = 0; kk2 < 2; ++kk2)
            #pragma unroll
            for (int nb = 0; nb < 2; ++nb) {
                int a0 = Q[nb][2 * kk2][0],     a1 = Q[nb][2 * kk2][1];
                int b0 = Q[nb][2 * kk2 + 1][0], b1 = Q[nb][2 * kk2 + 1][1];
                plswap(a0, b0);
                plswap(a1, b1);
                i32x4 pfi = { a0, a1, b0, b1 };
                bf16x8 pf = __builtin_bit_cast(bf16x8, pfi);
                hacc[nb][0] = mfma32(pf, vf[kk2 * 2 + 0], hacc[nb][0]);
                hacc[nb][1] = mfma32(pf, vf[kk2 * 2 + 1], hacc[nb][1]);
            }
    };

    bf16x8 efA[4], vfA[4], efB[4], vfB[4];
    f32x16 sTA[2], sTB[2];
    i32x2 Q[2][4];

    loadEF(0, efA); loadVF(0, vfA);
    loadEF(1, efB); loadVF(1, vfB);
    computeS(efA, sTA);

    for (int j = 0; j < 15; ++j) {
        loadEF(2 * j + 2, efA);
        computeS(efB, sTB);      // MFMA, tile 2j+1
        packQ(sTA, Q);           // VALU, tile 2j
        doPV(Q, vfA);            // MFMA, tile 2j
        loadVF(2 * j + 2, vfA);

        loadEF(2 * j + 3, efB);
        computeS(efA, sTA);      // MFMA, tile 2j+2
        packQ(sTB, Q);           // VALU, tile 2j+1
        doPV(Q, vfB);            // MFMA, tile 2j+1
        loadVF(2 * j + 3, vfB);
    }

    packQ(sTA, Q);
    doPV(Q, vfA);
    computeS(efB, sTB);
    packQ(sTB, Q);
    doPV(Q, vfB);

    // ---- epilogue: combine m-halves via LDS, add b3, store fp32 ----
    if (wm == 1) {
        #pragma unroll
        for (int nb = 0; nb < 2; ++nb)
            #pragma unroll
            for (int q = 0; q < 8; ++q) {
                f32x4 v;
                #pragma unroll
                for (int r = 0; r < 4; ++r) {
                    const int idx = q * 4 + r;          // 0..31
                    v[r] = hacc[nb][idx >> 4][idx & 15];
                }
                *(f32x4*)&scratch[nb * 2048 + q * 256 + l * 4] = v;
            }
    }
    __syncthreads();
    if (wm == 0) {
        #pragma unroll
        for (int nb = 0; nb < 2; ++nb)
            #pragma unroll
            for (int q = 0; q < 8; ++q) {
                f32x4 v = *(const f32x4*)&scratch[nb * 2048 + q * 256 + l * 4];
                #pragma unroll
                for (int r = 0; r < 4; ++r) {
                    const int idx = q * 4 + r;
                    hacc[nb][idx >> 4][idx & 15] += v[r];
                }
            }
        #pragma unroll
        for (int nb = 0; nb < 2; ++nb) {
            const size_t ob = ((size_t)bc * NN + nbase + nb * 32) * DD;
            #pragma unroll
            for (int reg = 0; reg < 16; ++reg) {
                const int n = (reg & 3) + 8 * (reg >> 2) + 4 * hi5;
                out[ob + (size_t)n * DD + l31]      = hacc[nb][0][reg] + bv0;
                out[ob + (size_t)n * DD + 32 + l31] = hacc[nb][1][reg] + bv1;
            }
        }
    }
}

extern "C" void kernel_launch(void* const* d_in, const int* in_sizes, int n_in,
                              void* d_out, int out_size, void* d_ws, size_t ws_size,
                              hipStream_t stream) {
    const float* x  = (const float*)d_in[0];
    const float* W1 = (const float*)d_in[1];
    const float* b1 = (const float*)d_in[2];
    const float* W2 = (const float*)d_in[3];
    const float* b2 = (const float*)d_in[4];
    const float* W3 = (const float*)d_in[5];
    const float* b3 = (const float*)d_in[6];
    float* out = (float*)d_out;

    __bf16* e1f = (__bf16*)d_ws;                      // 8 MB fragment-linear
    __bf16* e2f = e1f + (size_t)BCH * NN * DD;        // 8 MB fragment-linear
    __bf16* vtf = e2f + (size_t)BCH * NN * DD;        // 8 MB fragment-linear

    prep_kernel<<<dim3(1024), dim3(256), 0, stream>>>(x, W1, b1, W2, b2, W3, e1f, e2f, vtf);
    fused_kernel<<<dim3(1024), dim3(128), 0, stream>>>(e1f, e2f, vtf, b3, out);
}